// Round 4
// baseline (399.699 us; speedup 1.0000x reference)
//
#include <hip/hip_runtime.h>
#include <hip/hip_bf16.h>

#define OUTF 1024
#define NROWS 65536
#define NBR 4

typedef __attribute__((ext_vector_type(8))) short short8;
typedef __attribute__((ext_vector_type(4))) float f32x4;

__device__ inline unsigned short f2bf(float f) {
    return __builtin_bit_cast(unsigned short, (__bf16)f);
}
__device__ inline void gload_lds16(const void* g, void* l) {
    __builtin_amdgcn_global_load_lds(
        (const __attribute__((address_space(1))) void*)g,
        (__attribute__((address_space(3))) void*)l, 16, 0, 0);
}
__device__ inline short8 pack8(float4 a, float4 b) {
    short8 o;
    o[0] = (short)f2bf(a.x); o[1] = (short)f2bf(a.y);
    o[2] = (short)f2bf(a.z); o[3] = (short)f2bf(a.w);
    o[4] = (short)f2bf(b.x); o[5] = (short)f2bf(b.y);
    o[6] = (short)f2bf(b.z); o[7] = (short)f2bf(b.w);
    return o;
}

// ws int layout: [0..3] counts, [4..7] bases, [8..11] fill positions
__global__ void k_count(const int* __restrict__ feat, int* __restrict__ cnt) {
    __shared__ int lc[NBR];
    int tid = threadIdx.x;
    if (tid < NBR) lc[tid] = 0;
    __syncthreads();
    int r = blockIdx.x * 256 + tid;
    int b = 26 - __clz(feat[r]);  // 32->0, 64->1, 128->2, 256->3
    atomicAdd(&lc[b], 1);
    __syncthreads();
    if (tid < NBR && lc[tid]) atomicAdd(&cnt[tid], lc[tid]);
}

__global__ void k_prefix(int* __restrict__ ws) {
    if (threadIdx.x == 0) {
        int s = 0;
        for (int b = 0; b < NBR; b++) { ws[4 + b] = s; s += ws[b]; ws[8 + b] = 0; }
    }
}

__global__ void k_fill(const int* __restrict__ feat, int* __restrict__ ws,
                       int* __restrict__ rowlist) {
    int tid = threadIdx.x;
    int lane = tid & 63;
    int r = blockIdx.x * 256 + tid;
    int b = 26 - __clz(feat[r]);
    #pragma unroll
    for (int bb = 0; bb < NBR; bb++) {
        unsigned long long mask = __ballot(b == bb);
        int leader = __ffsll((long long)mask) - 1;
        int cntw = __popcll(mask);
        int basepos = 0;
        if (lane == leader) basepos = atomicAdd(&ws[8 + bb], cntw);
        basepos = __shfl(basepos, leader < 0 ? 0 : leader);
        if (b == bb) {
            int prefix = __popcll(mask & ((1ull << lane) - 1ull));
            rowlist[ws[4 + bb] + basepos + prefix] = r;
        }
    }
}

__global__ void k_convw(const float* __restrict__ w, unsigned short* __restrict__ wb) {
    int i = ((int)blockIdx.x * 256 + (int)threadIdx.x) * 4;
    const float4 v = *reinterpret_cast<const float4*>(w + i);
    ushort4 o;
    o.x = f2bf(v.x); o.y = f2bf(v.y); o.z = f2bf(v.z); o.w = f2bf(v.w);
    *reinterpret_cast<ushort4*>(wb + i) = o;
}

// 256x256x64 tile, 512 thr (2x4 waves), dbuf 128KiB LDS, 4-phase K-step.
// A: reg-staged fp32->bf16 (issue ph0, ds_write ph2); B: global_load_lds 16B.
// LDS swizzle: byte ^= ((row&7)<<4) on both source-gather and ds_read.
__global__ __launch_bounds__(512, 2)
void k_gemm3(const float* __restrict__ x,
             const unsigned short* __restrict__ wb,
             const float* __restrict__ bias,
             const int* __restrict__ ws_i,
             const int* __restrict__ rowlist,
             float* __restrict__ out) {
    extern __shared__ char lds[];

    // XCD-chunk swizzle (nwg = 1040, %8==0), M-tile-major within chunk
    const int d = (int)blockIdx.x;
    const int nwg = (int)gridDim.x;
    const int work = (d & 7) * (nwg >> 3) + (d >> 3);
    const int mtile = work >> 2;
    const int ntile = work & 3;

    int branch = -1, lt = 0, cnt = 0, rbase = 0;
    int t_ = mtile;
    #pragma unroll
    for (int b = 0; b < NBR; b++) {
        if (branch < 0) {
            int c = ws_i[b];
            int nt = (c + 255) >> 8;
            if (t_ < nt) { branch = b; lt = t_; cnt = c; rbase = ws_i[4 + b]; }
            else t_ -= nt;
        }
    }
    if (branch < 0) return;

    const int tid = threadIdx.x;
    const int lane = tid & 63;
    const int w = tid >> 6;
    const int wm = (w >> 2) * 128;   // wave M offset: 0/128
    const int wn = (w & 3) * 64;     // wave N offset: 0/64/128/192
    const int n0 = ntile * 256;

    // staging descriptors: thread covers LDS chunks Dl = i*8192 + w*1024 + lane*16
    const float4* pA[4];
    const char* gB[4];
    const int row0 = rbase + lt * 256;
    #pragma unroll
    for (int i = 0; i < 4; i++) {
        const int Dl = i * 8192 + w * 1024 + lane * 16;
        const int row = Dl >> 7;
        const int colb = (Dl & 127) ^ ((row & 7) << 4);  // inverse-swizzled source col (bytes, bf16)
        int idx = row0 + row;
        int grow = rowlist[idx < NROWS ? idx : 0];
        pA[i] = reinterpret_cast<const float4*>(x + (size_t)grow * OUTF + (colb >> 1));
        gB[i] = reinterpret_cast<const char*>(wb + ((size_t)branch << 20) + (size_t)(n0 + row) * OUTF) + colb;
    }

    f32x4 acc[8][4];
    #pragma unroll
    for (int i = 0; i < 8; i++)
        #pragma unroll
        for (int j = 0; j < 4; j++) acc[i][j] = (f32x4){0.f, 0.f, 0.f, 0.f};

    const int klane = (lane >> 4) << 4;      // k-chunk byte offset within 64B half-row
    const int swz = (lane & 7) << 4;         // read-side swizzle (row&7 == lane&7)
    const int arow = wm + (lane & 15);
    const int brow = wn + (lane & 15);

    // prologue: stage K-tile 0 into buf 0
    {
        char* A0 = lds;
        char* B0 = lds + 32768;
        #pragma unroll
        for (int i = 0; i < 4; i++) {
            float4 a0 = pA[i][0], a1 = pA[i][1];
            const int Dl = i * 8192 + w * 1024 + lane * 16;
            *reinterpret_cast<short8*>(A0 + Dl) = pack8(a0, a1);
        }
        #pragma unroll
        for (int i = 0; i < 4; i++)
            gload_lds16(gB[i], B0 + i * 8192 + w * 1024);
        __syncthreads();
    }

    short8 af[8], bfr[2];
    int cur = 0;

    for (int t = 0; t < 16; ++t) {
        const int nb = cur ^ 1;
        const bool st = (t < 15);
        char* Ac = lds + cur * 65536;
        char* Bc = Ac + 32768;
        char* An = lds + nb * 65536;
        char* Bn = An + 32768;
        float4 ra[4][2];

        // ---- phase 0 (kh=0, qn=0): issue A-src loads + 2 B gloads for t+1
        if (st) {
            #pragma unroll
            for (int i = 0; i < 4; i++) {
                ra[i][0] = pA[i][(t + 1) * 16];
                ra[i][1] = pA[i][(t + 1) * 16 + 1];
            }
            gload_lds16(gB[0] + (t + 1) * 128, Bn + 0 * 8192 + w * 1024);
            gload_lds16(gB[1] + (t + 1) * 128, Bn + 1 * 8192 + w * 1024);
        }
        #pragma unroll
        for (int fm = 0; fm < 8; fm++)
            af[fm] = *reinterpret_cast<const short8*>(Ac + (arow + fm * 16) * 128 + (klane ^ swz));
        #pragma unroll
        for (int fj = 0; fj < 2; fj++)
            bfr[fj] = *reinterpret_cast<const short8*>(Bc + (brow + fj * 16) * 128 + (klane ^ swz));
        __builtin_amdgcn_s_barrier();
        __builtin_amdgcn_s_setprio(1);
        #pragma unroll
        for (int fm = 0; fm < 8; fm++) {
            acc[fm][0] = __builtin_amdgcn_mfma_f32_16x16x32_bf16(af[fm], bfr[0], acc[fm][0], 0, 0, 0);
            acc[fm][1] = __builtin_amdgcn_mfma_f32_16x16x32_bf16(af[fm], bfr[1], acc[fm][1], 0, 0, 0);
        }
        __builtin_amdgcn_s_setprio(0);
        __builtin_amdgcn_s_barrier();

        // ---- phase 1 (kh=0, qn=1): issue remaining 2 B gloads
        if (st) {
            gload_lds16(gB[2] + (t + 1) * 128, Bn + 2 * 8192 + w * 1024);
            gload_lds16(gB[3] + (t + 1) * 128, Bn + 3 * 8192 + w * 1024);
        }
        #pragma unroll
        for (int fj = 0; fj < 2; fj++)
            bfr[fj] = *reinterpret_cast<const short8*>(Bc + (brow + 32 + fj * 16) * 128 + (klane ^ swz));
        __builtin_amdgcn_s_barrier();
        __builtin_amdgcn_s_setprio(1);
        #pragma unroll
        for (int fm = 0; fm < 8; fm++) {
            acc[fm][2] = __builtin_amdgcn_mfma_f32_16x16x32_bf16(af[fm], bfr[0], acc[fm][2], 0, 0, 0);
            acc[fm][3] = __builtin_amdgcn_mfma_f32_16x16x32_bf16(af[fm], bfr[1], acc[fm][3], 0, 0, 0);
        }
        __builtin_amdgcn_s_setprio(0);
        __builtin_amdgcn_s_barrier();

        // ---- phase 2 (kh=1, qn=0): cvt + ds_write A for t+1 (linear dest, conflict-free)
        if (st) {
            #pragma unroll
            for (int i = 0; i < 4; i++) {
                const int Dl = i * 8192 + w * 1024 + lane * 16;
                *reinterpret_cast<short8*>(An + Dl) = pack8(ra[i][0], ra[i][1]);
            }
        }
        #pragma unroll
        for (int fm = 0; fm < 8; fm++)
            af[fm] = *reinterpret_cast<const short8*>(Ac + (arow + fm * 16) * 128 + ((64 | klane) ^ swz));
        #pragma unroll
        for (int fj = 0; fj < 2; fj++)
            bfr[fj] = *reinterpret_cast<const short8*>(Bc + (brow + fj * 16) * 128 + ((64 | klane) ^ swz));
        __builtin_amdgcn_s_barrier();
        __builtin_amdgcn_s_setprio(1);
        #pragma unroll
        for (int fm = 0; fm < 8; fm++) {
            acc[fm][0] = __builtin_amdgcn_mfma_f32_16x16x32_bf16(af[fm], bfr[0], acc[fm][0], 0, 0, 0);
            acc[fm][1] = __builtin_amdgcn_mfma_f32_16x16x32_bf16(af[fm], bfr[1], acc[fm][1], 0, 0, 0);
        }
        __builtin_amdgcn_s_setprio(0);
        __builtin_amdgcn_s_barrier();

        // ---- phase 3 (kh=1, qn=1)
        #pragma unroll
        for (int fj = 0; fj < 2; fj++)
            bfr[fj] = *reinterpret_cast<const short8*>(Bc + (brow + 32 + fj * 16) * 128 + ((64 | klane) ^ swz));
        __builtin_amdgcn_s_barrier();
        __builtin_amdgcn_s_setprio(1);
        #pragma unroll
        for (int fm = 0; fm < 8; fm++) {
            acc[fm][2] = __builtin_amdgcn_mfma_f32_16x16x32_bf16(af[fm], bfr[0], acc[fm][2], 0, 0, 0);
            acc[fm][3] = __builtin_amdgcn_mfma_f32_16x16x32_bf16(af[fm], bfr[1], acc[fm][3], 0, 0, 0);
        }
        __builtin_amdgcn_s_setprio(0);
        __syncthreads();   // tile-end: drains vmcnt (B gloads) + lgkm (A ds_writes)
        cur ^= 1;
    }

    // epilogue: + bias, scatter to original rows. C/D map: col=lane&15, row=(lane>>4)*4+reg
    const int ccol = lane & 15;
    const int crow = (lane >> 4) << 2;
    float bv[4];
    const float* bp = bias + branch * OUTF + n0 + wn;
    #pragma unroll
    for (int fn = 0; fn < 4; fn++) bv[fn] = bp[fn * 16 + ccol];
    #pragma unroll
    for (int fm = 0; fm < 8; fm++) {
        #pragma unroll
        for (int j = 0; j < 4; j++) {
            int gm = lt * 256 + wm + fm * 16 + crow + j;
            if (gm < cnt) {
                int orow = rowlist[rbase + gm];
                float* orp = out + (size_t)orow * OUTF + n0 + wn;
                #pragma unroll
                for (int fn = 0; fn < 4; fn++)
                    orp[fn * 16 + ccol] = acc[fm][fn][j] + bv[fn];
            }
        }
    }
}

// ---------------- fallback (round-2 128^2 kernel) if ws is too small ----------------
template <bool USE_WB>
__global__ __launch_bounds__(256, 3)
void k_gemm_fb(const float* __restrict__ x,
               const unsigned short* __restrict__ wb,
               const float* __restrict__ wf,
               const float* __restrict__ bias,
               const int* __restrict__ ws_i,
               const int* __restrict__ rowlist,
               float* __restrict__ out) {
    __shared__ unsigned short As[128][72];
    __shared__ unsigned short Bs[128][72];

    int t = (int)blockIdx.x;
    int branch = -1, ltile = 0, cnt = 0, rbase = 0;
    #pragma unroll
    for (int b = 0; b < NBR; b++) {
        if (branch < 0) {
            int c = ws_i[b];
            int nt = (c + 127) >> 7;
            if (t < nt) { branch = b; ltile = t; cnt = c; rbase = ws_i[4 + b]; }
            else t -= nt;
        }
    }
    if (branch < 0) return;

    const int tid = threadIdx.x;
    const int lane = tid & 63;
    const int wid = tid >> 6;
    const int wm = (wid & 1) << 6;
    const int wn = (wid >> 1) << 6;
    const int n0 = (int)blockIdx.y * 128;

    const int srow = tid >> 1;
    const int scol = (tid & 1) << 5;

    const int gmrow = ltile * 128 + srow;
    const int grow = (gmrow < cnt) ? rowlist[rbase + gmrow] : -1;
    const float* xsrc = x + (size_t)(grow < 0 ? 0 : grow) * OUTF + scol;
    const unsigned short* wbsrc = wb + ((size_t)branch << 20) + (size_t)(n0 + srow) * OUTF + scol;
    const float* wfsrc = wf + ((size_t)branch << 20) + (size_t)(n0 + srow) * OUTF + scol;

    f32x4 acc[4][4];
    #pragma unroll
    for (int i = 0; i < 4; i++)
        #pragma unroll
        for (int j = 0; j < 4; j++)
            acc[i][j] = (f32x4){0.f, 0.f, 0.f, 0.f};

    for (int k0 = 0; k0 < OUTF; k0 += 64) {
        {
            unsigned short* dst = &As[srow][scol];
            if (grow >= 0) {
                const float4* s4 = reinterpret_cast<const float4*>(xsrc + k0);
                #pragma unroll
                for (int i = 0; i < 8; i++) {
                    float4 v = s4[i];
                    ushort4 o;
                    o.x = f2bf(v.x); o.y = f2bf(v.y); o.z = f2bf(v.z); o.w = f2bf(v.w);
                    reinterpret_cast<ushort4*>(dst)[i] = o;
                }
            } else {
                ushort4 z; z.x = z.y = z.z = z.w = 0;
                #pragma unroll
                for (int i = 0; i < 8; i++) reinterpret_cast<ushort4*>(dst)[i] = z;
            }
        }
        {
            unsigned short* dst = &Bs[srow][scol];
            if (USE_WB) {
                const int4* s4 = reinterpret_cast<const int4*>(wbsrc + k0);
                #pragma unroll
                for (int i = 0; i < 4; i++) reinterpret_cast<int4*>(dst)[i] = s4[i];
            } else {
                const float4* s4 = reinterpret_cast<const float4*>(wfsrc + k0);
                #pragma unroll
                for (int i = 0; i < 8; i++) {
                    float4 v = s4[i];
                    ushort4 o;
                    o.x = f2bf(v.x); o.y = f2bf(v.y); o.z = f2bf(v.z); o.w = f2bf(v.w);
                    reinterpret_cast<ushort4*>(dst)[i] = o;
                }
            }
        }
        __syncthreads();
        #pragma unroll
        for (int kk = 0; kk < 64; kk += 32) {
            const int krd = kk + (lane >> 4) * 8;
            short8 af[4], bf_[4];
            #pragma unroll
            for (int i = 0; i < 4; i++)
                af[i] = *reinterpret_cast<const short8*>(&As[wm + i * 16 + (lane & 15)][krd]);
            #pragma unroll
            for (int i = 0; i < 4; i++)
                bf_[i] = *reinterpret_cast<const short8*>(&Bs[wn + i * 16 + (lane & 15)][krd]);
            #pragma unroll
            for (int i = 0; i < 4; i++)
                #pragma unroll
                for (int j = 0; j < 4; j++)
                    acc[i][j] = __builtin_amdgcn_mfma_f32_16x16x32_bf16(af[i], bf_[j], acc[i][j], 0, 0, 0);
        }
        __syncthreads();
    }

    const int ccol = lane & 15;
    const int crow = (lane >> 4) << 2;
    float bv[4];
    const float* bp = bias + branch * OUTF + n0 + wn;
    #pragma unroll
    for (int fn = 0; fn < 4; fn++) bv[fn] = bp[fn * 16 + ccol];
    #pragma unroll
    for (int fm = 0; fm < 4; fm++) {
        #pragma unroll
        for (int j = 0; j < 4; j++) {
            int gm = ltile * 128 + wm + fm * 16 + crow + j;
            if (gm < cnt) {
                int orow = rowlist[rbase + gm];
                float* orp = out + (size_t)orow * OUTF + n0 + wn;
                #pragma unroll
                for (int fn = 0; fn < 4; fn++)
                    orp[fn * 16 + ccol] = acc[fm][fn][j] + bv[fn];
            }
        }
    }
}

extern "C" void kernel_launch(void* const* d_in, const int* in_sizes, int n_in,
                              void* d_out, int out_size, void* d_ws, size_t ws_size,
                              hipStream_t stream) {
    const float* x = (const float*)d_in[0];
    const int* feat = (const int*)d_in[1];
    const float* w = (const float*)d_in[2];
    const float* bias = (const float*)d_in[3];
    float* out = (float*)d_out;

    char* ws = (char*)d_ws;
    int* ws_i = (int*)ws;
    int* rowlist = (int*)(ws + 256);
    const size_t WB_OFF = (size_t)512 << 10;  // 512 KB (header + rowlist below)
    unsigned short* wb = (unsigned short*)(ws + WB_OFF);
    const size_t need_wb = WB_OFF + (size_t)NBR * OUTF * OUTF * 2;  // ~8.9 MB

    (void)hipMemsetAsync(ws_i, 0, 64, stream);
    k_count<<<NROWS / 256, 256, 0, stream>>>(feat, ws_i);
    k_prefix<<<1, 64, 0, stream>>>(ws_i);
    k_fill<<<NROWS / 256, 256, 0, stream>>>(feat, ws_i, rowlist);

    if (ws_size >= need_wb) {
        k_convw<<<(NBR * OUTF * OUTF) / (256 * 4), 256, 0, stream>>>(w, wb);
        const int nwg = (NROWS / 256 + NBR) * 4;  // 260*4 = 1040, %8==0
        (void)hipFuncSetAttribute((const void*)k_gemm3,
                                  hipFuncAttributeMaxDynamicSharedMemorySize, 131072);
        k_gemm3<<<nwg, 512, 131072, stream>>>(x, wb, bias, ws_i, rowlist, out);
    } else {
        dim3 grid(NROWS / 128 + NBR, OUTF / 128);
        k_gemm_fb<false><<<grid, 256, 0, stream>>>(x, wb, w, bias, ws_i, rowlist, out);
    }
}

// Round 5
// 358.933 us; speedup vs baseline: 1.1136x; 1.1136x over previous
//
#include <hip/hip_runtime.h>
#include <hip/hip_bf16.h>

#define OUTF 1024
#define NROWS 65536
#define NBR 4
#define BM 128
#define BN 256
#define BK 64
#define KITERS 16          // OUTF/BK
#define ABYTES 16384       // BM*BK*2
#define BBYTES 32768       // BN*BK*2
#define BUFB 49152         // ABYTES+BBYTES
#define NWG 2064           // (512+4) M-tiles * 4 N-tiles, %8==0

typedef __attribute__((ext_vector_type(8))) short short8;
typedef __attribute__((ext_vector_type(4))) float f32x4;

__device__ inline unsigned short f2bf(float f) {
    return __builtin_bit_cast(unsigned short, (__bf16)f);
}
__device__ inline void gload_lds16(const void* g, void* l) {
    __builtin_amdgcn_global_load_lds(
        (const __attribute__((address_space(1))) void*)g,
        (__attribute__((address_space(3))) void*)l, 16, 0, 0);
}
__device__ inline short8 pack8(float4 a, float4 b) {
    short8 o;
    o[0] = (short)f2bf(a.x); o[1] = (short)f2bf(a.y);
    o[2] = (short)f2bf(a.z); o[3] = (short)f2bf(a.w);
    o[4] = (short)f2bf(b.x); o[5] = (short)f2bf(b.y);
    o[6] = (short)f2bf(b.z); o[7] = (short)f2bf(b.w);
    return o;
}

// ws int layout: [0..3] counts, [4..7] bases, [8..11] fill positions
__global__ void k_count(const int* __restrict__ feat, int* __restrict__ cnt) {
    __shared__ int lc[NBR];
    int tid = threadIdx.x;
    if (tid < NBR) lc[tid] = 0;
    __syncthreads();
    int r = blockIdx.x * 256 + tid;
    int b = 26 - __clz(feat[r]);  // 32->0, 64->1, 128->2, 256->3
    atomicAdd(&lc[b], 1);
    __syncthreads();
    if (tid < NBR && lc[tid]) atomicAdd(&cnt[tid], lc[tid]);
}

__global__ void k_prefix(int* __restrict__ ws) {
    if (threadIdx.x == 0) {
        int s = 0;
        for (int b = 0; b < NBR; b++) { ws[4 + b] = s; s += ws[b]; ws[8 + b] = 0; }
    }
}

__global__ void k_fill(const int* __restrict__ feat, int* __restrict__ ws,
                       int* __restrict__ rowlist) {
    int tid = threadIdx.x;
    int lane = tid & 63;
    int r = blockIdx.x * 256 + tid;
    int b = 26 - __clz(feat[r]);
    #pragma unroll
    for (int bb = 0; bb < NBR; bb++) {
        unsigned long long mask = __ballot(b == bb);
        int leader = __ffsll((long long)mask) - 1;
        int cntw = __popcll(mask);
        int basepos = 0;
        if (lane == leader) basepos = atomicAdd(&ws[8 + bb], cntw);
        basepos = __shfl(basepos, leader < 0 ? 0 : leader);
        if (b == bb) {
            int prefix = __popcll(mask & ((1ull << lane) - 1ull));
            rowlist[ws[4 + bb] + basepos + prefix] = r;
        }
    }
}

// W fp32 -> bf16, PRE-SWIZZLED so that linear global_load_lds + swizzled ds_read
// sees: lds[row*128 + (cb ^ ((row&7)<<4))] == W[n][kw*64 + cb/2].
// Store: wsw[branch][n][kw*128 + cb] = bf16(W[branch][n][kw*64 + ((cb^((n&7)<<4))>>1)])
__global__ void k_convw(const float* __restrict__ w, unsigned short* __restrict__ wsw) {
    int idx = (int)blockIdx.x * 256 + (int)threadIdx.x;   // 0..524287, 16B each
    int branch = idx >> 17;
    int rem = idx & 131071;
    int n = rem >> 7;
    int c8 = rem & 127;
    int cb = c8 << 4;                 // byte col within 2048B row
    int kw = cb >> 7;                 // 128B K-window
    int wb_ = cb & 127;
    int src = kw * 64 + (((wb_) ^ ((n & 7) << 4)) >> 1);  // fp32 col
    const float4* s = reinterpret_cast<const float4*>(
        w + ((size_t)branch << 20) + (size_t)n * OUTF + src);
    float4 v0 = s[0], v1 = s[1];
    char* dst = reinterpret_cast<char*>(wsw) + ((size_t)branch << 21) + (size_t)n * 2048 + cb;
    *reinterpret_cast<short8*>(dst) = pack8(v0, v1);
}

// 128x256x64 tile, 8 waves (2M x 4N), 3-buffer LDS (144 KiB), 2-tiles-ahead
// counted-vmcnt pipeline. A: reg-staged fp32->bf16 (issue t+2, write t+1);
// B: global_load_lds from pre-swizzled wsw. One barrier per K-tile.
__global__ __launch_bounds__(512, 2)
void k_gemm4(const float* __restrict__ x,
             const unsigned short* __restrict__ wsw,
             const float* __restrict__ bias,
             const int* __restrict__ ws_i,
             const int* __restrict__ rowlist,
             float* __restrict__ out) {
    extern __shared__ char lds[];

    // XCD-chunk swizzle, M-tile-major within chunk (panel L2 reuse)
    const int d = (int)blockIdx.x;
    const int work = (d & 7) * (NWG >> 3) + (d >> 3);
    const int mtile = work >> 2;
    const int ntile = work & 3;

    int branch = -1, lt = 0, cnt = 0, rbase = 0;
    int t_ = mtile;
    #pragma unroll
    for (int b = 0; b < NBR; b++) {
        if (branch < 0) {
            int c = ws_i[b];
            int nt = (c + 127) >> 7;
            if (t_ < nt) { branch = b; lt = t_; cnt = c; rbase = ws_i[4 + b]; }
            else t_ -= nt;
        }
    }
    if (branch < 0) return;

    const int tid = threadIdx.x;
    const int lane = tid & 63;
    const int w8 = tid >> 6;
    const int wm = (w8 >> 2) * 64;    // 0/64
    const int wn = (w8 & 3) * 64;     // 0/64/128/192
    const int n0 = ntile * BN;

    // ---- A staging: thread covers row tid>>2, 16 fp32 cols at (tid&3)*16
    const int sarow = tid >> 2;
    const int sacol = (tid & 3) << 4;
    int aridx = rbase + lt * BM + sarow;
    int agrow = rowlist[aridx < NROWS ? aridx : 0];
    const float4* pa = reinterpret_cast<const float4*>(x + (size_t)agrow * OUTF + sacol);
    const int awb0 = sarow * 128 + (((tid & 3) * 32) ^ ((sarow & 7) << 4));
    const int awb1 = sarow * 128 + ((((tid & 3) * 32) + 16) ^ ((sarow & 7) << 4));

    // ---- B staging: 4 gloads; LDS off i*8192 + tid*16; src row i*64+(tid>>3)
    const char* gb[4];
    #pragma unroll
    for (int i = 0; i < 4; i++) {
        int brow_ = i * 64 + (tid >> 3);
        gb[i] = reinterpret_cast<const char*>(wsw) + ((size_t)branch << 21)
                + (size_t)(n0 + brow_) * 2048 + ((tid & 7) << 4);
    }
    const int ldsoffB = tid * 16;

    f32x4 acc[4][4];
    #pragma unroll
    for (int i = 0; i < 4; i++)
        #pragma unroll
        for (int j = 0; j < 4; j++) acc[i][j] = (f32x4){0.f, 0.f, 0.f, 0.f};

    const int swz = (lane & 7) << 4;
    const int kq = (lane >> 4) << 4;          // 0..48 byte
    const int arowb = (wm + (lane & 15)) * 128;
    const int browb = (wn + (lane & 15)) * 128;

    float4 ra[4], rn[4];

    // ---- prologue: tile0 staged fully, tile1 in flight
    #pragma unroll
    for (int i = 0; i < 4; i++) ra[i] = pa[i];
    #pragma unroll
    for (int i = 0; i < 4; i++)
        gload_lds16(gb[i], lds + ABYTES + i * 8192 + ldsoffB);
    *reinterpret_cast<short8*>(lds + awb0) = pack8(ra[0], ra[1]);
    *reinterpret_cast<short8*>(lds + awb1) = pack8(ra[2], ra[3]);
    #pragma unroll
    for (int i = 0; i < 4; i++) ra[i] = pa[16 + i];
    #pragma unroll
    for (int i = 0; i < 4; i++)
        gload_lds16(gb[i] + 128, lds + BUFB + ABYTES + i * 8192 + ldsoffB);
    asm volatile("s_waitcnt vmcnt(8) lgkmcnt(0)" ::: "memory");
    __builtin_amdgcn_sched_barrier(0);
    __builtin_amdgcn_s_barrier();
    __builtin_amdgcn_sched_barrier(0);

    short8 af[4], bf_[4];

    for (int t = 0; t < KITERS; ++t) {
        char* Ac = lds + (t % 3) * BUFB;
        char* Bc = Ac + ABYTES;

        // issue tile t+2 (A to regs, B to buf[(t+2)%3] — not read this iter)
        if (t < KITERS - 2) {
            #pragma unroll
            for (int i = 0; i < 4; i++) rn[i] = pa[(t + 2) * 16 + i];
            char* Bn = lds + ((t + 2) % 3) * BUFB + ABYTES;
            #pragma unroll
            for (int i = 0; i < 4; i++)
                gload_lds16(gb[i] + (t + 2) * 128, Bn + i * 8192 + ldsoffB);
        }
        // cvt + ds_write tile t+1 A (loads issued last iter -> latency covered)
        if (t < KITERS - 1) {
            char* An = lds + ((t + 1) % 3) * BUFB;
            *reinterpret_cast<short8*>(An + awb0) = pack8(ra[0], ra[1]);
            *reinterpret_cast<short8*>(An + awb1) = pack8(ra[2], ra[3]);
        }
        // compute tile t
        #pragma unroll
        for (int kh = 0; kh < 2; kh++) {
            const int kb = kh * 64 + kq;
            #pragma unroll
            for (int i = 0; i < 4; i++)
                af[i] = *reinterpret_cast<const short8*>(Ac + arowb + i * 2048 + (kb ^ swz));
            #pragma unroll
            for (int i = 0; i < 4; i++)
                bf_[i] = *reinterpret_cast<const short8*>(Bc + browb + i * 2048 + (kb ^ swz));
            __builtin_amdgcn_s_setprio(1);
            #pragma unroll
            for (int i = 0; i < 4; i++)
                #pragma unroll
                for (int j = 0; j < 4; j++)
                    acc[i][j] = __builtin_amdgcn_mfma_f32_16x16x32_bf16(af[i], bf_[j], acc[i][j], 0, 0, 0);
            __builtin_amdgcn_s_setprio(0);
        }
        #pragma unroll
        for (int i = 0; i < 4; i++) ra[i] = rn[i];

        // end-of-tile: allow this iter's 8 issues outstanding; all older drained.
        if (t < KITERS - 2) {
            asm volatile("s_waitcnt vmcnt(8) lgkmcnt(0)" ::: "memory");
        } else {
            asm volatile("s_waitcnt vmcnt(0) lgkmcnt(0)" ::: "memory");
        }
        __builtin_amdgcn_sched_barrier(0);
        __builtin_amdgcn_s_barrier();
        __builtin_amdgcn_sched_barrier(0);
    }

    // epilogue: + bias, scatter. C/D map: col=lane&15, row=(lane>>4)*4+reg
    const int ccol = lane & 15;
    const int crow = (lane >> 4) << 2;
    float bv[4];
    const float* bp = bias + branch * OUTF + n0 + wn;
    #pragma unroll
    for (int fn = 0; fn < 4; fn++) bv[fn] = bp[fn * 16 + ccol];
    #pragma unroll
    for (int fm = 0; fm < 4; fm++) {
        #pragma unroll
        for (int j = 0; j < 4; j++) {
            int gm = lt * BM + wm + fm * 16 + crow + j;
            if (gm < cnt) {
                int orow = rowlist[rbase + gm];
                float* orp = out + (size_t)orow * OUTF + n0 + wn;
                #pragma unroll
                for (int fn = 0; fn < 4; fn++)
                    orp[fn * 16 + ccol] = acc[fm][fn][j] + bv[fn];
            }
        }
    }
}

// ---------------- fallback (round-1 style, fp32 W) if ws is too small ----------------
__global__ __launch_bounds__(256, 3)
void k_gemm_fb(const float* __restrict__ x,
               const float* __restrict__ wf,
               const float* __restrict__ bias,
               const int* __restrict__ ws_i,
               const int* __restrict__ rowlist,
               float* __restrict__ out) {
    __shared__ unsigned short As[128][72];
    __shared__ unsigned short Bs[128][72];

    int t = (int)blockIdx.x;
    int branch = -1, ltile = 0, cnt = 0, rbase = 0;
    #pragma unroll
    for (int b = 0; b < NBR; b++) {
        if (branch < 0) {
            int c = ws_i[b];
            int nt = (c + 127) >> 7;
            if (t < nt) { branch = b; ltile = t; cnt = c; rbase = ws_i[4 + b]; }
            else t -= nt;
        }
    }
    if (branch < 0) return;

    const int tid = threadIdx.x;
    const int lane = tid & 63;
    const int wid = tid >> 6;
    const int wm = (wid & 1) << 6;
    const int wn = (wid >> 1) << 6;
    const int n0 = (int)blockIdx.y * 128;

    const int srow = tid >> 1;
    const int scol = (tid & 1) << 5;

    const int gmrow = ltile * 128 + srow;
    const int grow = (gmrow < cnt) ? rowlist[rbase + gmrow] : -1;
    const float* xsrc = x + (size_t)(grow < 0 ? 0 : grow) * OUTF + scol;
    const float* wfsrc = wf + ((size_t)branch << 20) + (size_t)(n0 + srow) * OUTF + scol;

    f32x4 acc[4][4];
    #pragma unroll
    for (int i = 0; i < 4; i++)
        #pragma unroll
        for (int j = 0; j < 4; j++)
            acc[i][j] = (f32x4){0.f, 0.f, 0.f, 0.f};

    for (int k0 = 0; k0 < OUTF; k0 += 64) {
        {
            unsigned short* dst = &As[srow][scol];
            if (grow >= 0) {
                const float4* s4 = reinterpret_cast<const float4*>(xsrc + k0);
                #pragma unroll
                for (int i = 0; i < 8; i++) {
                    float4 v = s4[i];
                    ushort4 o;
                    o.x = f2bf(v.x); o.y = f2bf(v.y); o.z = f2bf(v.z); o.w = f2bf(v.w);
                    reinterpret_cast<ushort4*>(dst)[i] = o;
                }
            } else {
                ushort4 z; z.x = z.y = z.z = z.w = 0;
                #pragma unroll
                for (int i = 0; i < 8; i++) reinterpret_cast<ushort4*>(dst)[i] = z;
            }
        }
        {
            unsigned short* dst = &Bs[srow][scol];
            const float4* s4 = reinterpret_cast<const float4*>(wfsrc + k0);
            #pragma unroll
            for (int i = 0; i < 8; i++) {
                float4 v = s4[i];
                ushort4 o;
                o.x = f2bf(v.x); o.y = f2bf(v.y); o.z = f2bf(v.z); o.w = f2bf(v.w);
                reinterpret_cast<ushort4*>(dst)[i] = o;
            }
        }
        __syncthreads();
        #pragma unroll
        for (int kk = 0; kk < 64; kk += 32) {
            const int krd = kk + (lane >> 4) * 8;
            short8 af[4], bf_[4];
            #pragma unroll
            for (int i = 0; i < 4; i++)
                af[i] = *reinterpret_cast<const short8*>(&As[wm + i * 16 + (lane & 15)][krd]);
            #pragma unroll
            for (int i = 0; i < 4; i++)
                bf_[i] = *reinterpret_cast<const short8*>(&Bs[wn + i * 16 + (lane & 15)][krd]);
            #pragma unroll
            for (int i = 0; i < 4; i++)
                #pragma unroll
                for (int j = 0; j < 4; j++)
                    acc[i][j] = __builtin_amdgcn_mfma_f32_16x16x32_bf16(af[i], bf_[j], acc[i][j], 0, 0, 0);
        }
        __syncthreads();
    }

    const int ccol = lane & 15;
    const int crow = (lane >> 4) << 2;
    float bv[4];
    const float* bp = bias + branch * OUTF + n0 + wn;
    #pragma unroll
    for (int fn = 0; fn < 4; fn++) bv[fn] = bp[fn * 16 + ccol];
    #pragma unroll
    for (int fm = 0; fm < 4; fm++) {
        #pragma unroll
        for (int j = 0; j < 4; j++) {
            int gm = ltile * 128 + wm + fm * 16 + crow + j;
            if (gm < cnt) {
                int orow = rowlist[rbase + gm];
                float* orp = out + (size_t)orow * OUTF + n0 + wn;
                #pragma unroll
                for (int fn = 0; fn < 4; fn++)
                    orp[fn * 16 + ccol] = acc[fm][fn][j] + bv[fn];
            }
        }
    }
}

extern "C" void kernel_launch(void* const* d_in, const int* in_sizes, int n_in,
                              void* d_out, int out_size, void* d_ws, size_t ws_size,
                              hipStream_t stream) {
    const float* x = (const float*)d_in[0];
    const int* feat = (const int*)d_in[1];
    const float* w = (const float*)d_in[2];
    const float* bias = (const float*)d_in[3];
    float* out = (float*)d_out;

    char* ws = (char*)d_ws;
    int* ws_i = (int*)ws;
    int* rowlist = (int*)(ws + 256);
    const size_t WB_OFF = (size_t)512 << 10;
    unsigned short* wsw = (unsigned short*)(ws + WB_OFF);
    const size_t need = WB_OFF + (size_t)NBR * OUTF * OUTF * 2;  // ~8.9 MB

    (void)hipMemsetAsync(ws_i, 0, 64, stream);
    k_count<<<NROWS / 256, 256, 0, stream>>>(feat, ws_i);
    k_prefix<<<1, 64, 0, stream>>>(ws_i);
    k_fill<<<NROWS / 256, 256, 0, stream>>>(feat, ws_i, rowlist);

    if (ws_size >= need) {
        k_convw<<<2048, 256, 0, stream>>>(w, wsw);
        (void)hipFuncSetAttribute((const void*)k_gemm4,
                                  hipFuncAttributeMaxDynamicSharedMemorySize, 3 * BUFB);
        k_gemm4<<<NWG, 512, 3 * BUFB, stream>>>(x, wsw, bias, ws_i, rowlist, out);
    } else {
        dim3 grid(NROWS / 128 + NBR, OUTF / 128);
        k_gemm_fb<<<grid, 256, 0, stream>>>(x, w, bias, ws_i, rowlist, out);
    }
}

// Round 6
// 352.340 us; speedup vs baseline: 1.1344x; 1.0187x over previous
//
#include <hip/hip_runtime.h>
#include <hip/hip_bf16.h>

#define OUTF 1024
#define NROWS 65536
#define NBR 4
#define XBROWS 66560     // 256-aligned branch segments: <= 65536 + 4*255, padded
#define NWG 1040         // 260 M-tiles * 4 N-tiles, %8==0

typedef __attribute__((ext_vector_type(8))) short short8;
typedef __attribute__((ext_vector_type(4))) float f32x4;

__device__ inline unsigned short f2bf(float f) {
    return __builtin_bit_cast(unsigned short, (__bf16)f);
}
__device__ inline void gload_lds16(const void* g, void* l) {
    __builtin_amdgcn_global_load_lds(
        (const __attribute__((address_space(1))) void*)g,
        (__attribute__((address_space(3))) void*)l, 16, 0, 0);
}
__device__ inline short8 pack8(float4 a, float4 b) {
    short8 o;
    o[0] = (short)f2bf(a.x); o[1] = (short)f2bf(a.y);
    o[2] = (short)f2bf(a.z); o[3] = (short)f2bf(a.w);
    o[4] = (short)f2bf(b.x); o[5] = (short)f2bf(b.y);
    o[6] = (short)f2bf(b.z); o[7] = (short)f2bf(b.w);
    return o;
}

// ws int layout: [0..3] counts, [4..7] segment bases (256-aligned), [8..11] fill pos
__global__ void k_count(const int* __restrict__ feat, int* __restrict__ cnt) {
    __shared__ int lc[NBR];
    int tid = threadIdx.x;
    if (tid < NBR) lc[tid] = 0;
    __syncthreads();
    int r = blockIdx.x * 256 + tid;
    int b = 26 - __clz(feat[r]);  // 32->0, 64->1, 128->2, 256->3
    atomicAdd(&lc[b], 1);
    __syncthreads();
    if (tid < NBR && lc[tid]) atomicAdd(&cnt[tid], lc[tid]);
}

__global__ void k_prefix(int* __restrict__ ws) {
    if (threadIdx.x == 0) {
        int s = 0;
        for (int b = 0; b < NBR; b++) {
            ws[4 + b] = s;
            s = (s + ws[b] + 255) & ~255;  // 256-align each segment start
            ws[8 + b] = 0;
        }
    }
}

__global__ void k_fill(const int* __restrict__ feat, int* __restrict__ ws,
                       int* __restrict__ rowlist) {
    int tid = threadIdx.x;
    int lane = tid & 63;
    int r = blockIdx.x * 256 + tid;
    int b = 26 - __clz(feat[r]);
    #pragma unroll
    for (int bb = 0; bb < NBR; bb++) {
        unsigned long long mask = __ballot(b == bb);
        int leader = __ffsll((long long)mask) - 1;
        int cntw = __popcll(mask);
        int basepos = 0;
        if (lane == leader) basepos = atomicAdd(&ws[8 + bb], cntw);
        basepos = __shfl(basepos, leader < 0 ? 0 : leader);
        if (b == bb) {
            int prefix = __popcll(mask & ((1ull << lane) - 1ull));
            rowlist[ws[4 + bb] + basepos + prefix] = r;
        }
    }
}

// W fp32 -> bf16, pre-swizzled: wsw[br][n][kw*128+cb] = bf16(W[br][n][kw*64+((cb^((n&7)<<4))>>1)])
__global__ void k_convw(const float* __restrict__ w, unsigned short* __restrict__ wsw) {
    int idx = (int)blockIdx.x * 256 + (int)threadIdx.x;   // 16B chunks
    int branch = idx >> 17;
    int rem = idx & 131071;
    int n = rem >> 7;
    int cb = (rem & 127) << 4;
    int kw = cb >> 7;
    int wb_ = cb & 127;
    int src = kw * 64 + ((wb_ ^ ((n & 7) << 4)) >> 1);
    const float4* s = reinterpret_cast<const float4*>(
        w + ((size_t)branch << 20) + (size_t)n * OUTF + src);
    char* dst = reinterpret_cast<char*>(wsw) + ((size_t)branch << 21) + (size_t)n * 2048 + cb;
    *reinterpret_cast<short8*>(dst) = pack8(s[0], s[1]);
}

// x fp32 -> bf16, gathered into permuted (branch-contiguous, 256-aligned) order,
// pre-swizzled identically to W: xb[row][kw*128+cb] = bf16(x[rl[row]][kw*64+((cb^((row&7)<<4))>>1)])
__global__ void k_convx(const float* __restrict__ x, const int* __restrict__ rowlist,
                        unsigned short* __restrict__ xb) {
    int g = (int)blockIdx.x * 512 + (int)threadIdx.x;   // 16B chunks, XBROWS*128 total
    int orow = g >> 7;
    int cb = (g & 127) << 4;
    int rl = rowlist[orow];
    if ((unsigned)rl >= NROWS) rl = 0;   // segment pad gap: any garbage -> row 0
    int kw = cb >> 7;
    int wb_ = cb & 127;
    int src = kw * 64 + ((wb_ ^ ((orow & 7) << 4)) >> 1);
    const float4* s = reinterpret_cast<const float4*>(x + (size_t)rl * OUTF + src);
    char* dst = reinterpret_cast<char*>(xb) + (size_t)orow * 2048 + cb;
    *reinterpret_cast<short8*>(dst) = pack8(s[0], s[1]);
}

// 256x256x64 GEMM, 8 waves (2M x 4N), all-gload_lds staging.
// LDS: A 3-deep (3x32K) + B 2-deep (2x32K) = 160 KiB.
// Per iter t: issue B(t+1) then A(t+2); compute t; s_waitcnt vmcnt(4); barrier.
// vmcnt(4) leaves only A(t+2)'s 4 loads in flight -> A spans ~2 iters (HBM-tolerant),
// B spans ~1 iter (L2-resident weights), nothing ever fully drains until the tail.
__global__ __launch_bounds__(512, 2)
void k_gemm5(const unsigned short* __restrict__ xb,
             const unsigned short* __restrict__ wsw,
             const float* __restrict__ bias,
             const int* __restrict__ ws_i,
             const int* __restrict__ rowlist,
             float* __restrict__ out) {
    extern __shared__ char lds[];

    // XCD-chunk swizzle, M-tile-major within chunk (A-panel L2 reuse across 4 N-tiles)
    const int d = (int)blockIdx.x;
    const int work = (d & 7) * (NWG >> 3) + (d >> 3);
    const int mtile = work >> 2;
    const int ntile = work & 3;

    int branch = -1, lt = 0, cnt = 0, rbase = 0;
    int t_ = mtile;
    #pragma unroll
    for (int b = 0; b < NBR; b++) {
        if (branch < 0) {
            int c = ws_i[b];
            int nt = (c + 255) >> 8;
            if (t_ < nt) { branch = b; lt = t_; cnt = c; rbase = ws_i[4 + b]; }
            else t_ -= nt;
        }
    }
    if (branch < 0) return;

    const int tid = threadIdx.x;
    const int lane = tid & 63;
    const int w8 = tid >> 6;
    const int wm = (w8 >> 2) * 128;   // 0/128
    const int wn = (w8 & 3) * 64;     // 0/64/128/192
    const int n0 = ntile * 256;
    const int row0 = rbase + lt * 256;   // row0 % 256 == 0 -> swizzle position-independent

    // staging sources: gload i covers rows i*64 + (tid>>3), 16B col (tid&7)*16
    const char* gA[4];
    const char* gB[4];
    #pragma unroll
    for (int i = 0; i < 4; i++) {
        int r = i * 64 + (tid >> 3);
        gA[i] = reinterpret_cast<const char*>(xb) + (size_t)(row0 + r) * 2048 + ((tid & 7) << 4);
        gB[i] = reinterpret_cast<const char*>(wsw) + ((size_t)branch << 21)
                + (size_t)(n0 + r) * 2048 + ((tid & 7) << 4);
    }
    const int ldsoff = tid << 4;

    f32x4 acc[8][4];
    #pragma unroll
    for (int i = 0; i < 8; i++)
        #pragma unroll
        for (int j = 0; j < 4; j++) acc[i][j] = (f32x4){0.f, 0.f, 0.f, 0.f};

    const int swz = (lane & 7) << 4;
    const int kq = (lane >> 4) << 4;
    const int arowb = (wm + (lane & 15)) * 128;
    const int browb = (wn + (lane & 15)) * 128;

    // prologue: A(0)->bufA0, A(1)->bufA1, B(0)->bufB0, full drain once
    #pragma unroll
    for (int i = 0; i < 4; i++) gload_lds16(gA[i], lds + i * 8192 + ldsoff);
    #pragma unroll
    for (int i = 0; i < 4; i++) gload_lds16(gA[i] + 128, lds + 32768 + i * 8192 + ldsoff);
    #pragma unroll
    for (int i = 0; i < 4; i++) gload_lds16(gB[i], lds + 98304 + i * 8192 + ldsoff);
    asm volatile("s_waitcnt vmcnt(0)" ::: "memory");
    __builtin_amdgcn_sched_barrier(0);
    __builtin_amdgcn_s_barrier();
    __builtin_amdgcn_sched_barrier(0);

    int ia = 0;  // t % 3
    for (int t = 0; t < 16; ++t) {
        char* Ac = lds + ia * 32768;
        char* Bc = lds + 98304 + (t & 1) * 32768;

        if (t < 15) {   // B(t+1) -> other B buf
            char* Bn = lds + 98304 + ((t + 1) & 1) * 32768;
            #pragma unroll
            for (int i = 0; i < 4; i++)
                gload_lds16(gB[i] + (t + 1) * 128, Bn + i * 8192 + ldsoff);
        }
        if (t < 14) {   // A(t+2) -> bufA[(t+2)%3]
            int ia2 = ia + 2; if (ia2 >= 3) ia2 -= 3;
            char* An = lds + ia2 * 32768;
            #pragma unroll
            for (int i = 0; i < 4; i++)
                gload_lds16(gA[i] + (t + 2) * 128, An + i * 8192 + ldsoff);
        }
        __builtin_amdgcn_sched_barrier(0);

        __builtin_amdgcn_s_setprio(1);
        #pragma unroll
        for (int ks = 0; ks < 2; ks++) {
            const int kb = (ks << 6) + kq;
            short8 af[8], bf_[4];
            #pragma unroll
            for (int i = 0; i < 8; i++)
                af[i] = *reinterpret_cast<const short8*>(Ac + arowb + i * 2048 + (kb ^ swz));
            #pragma unroll
            for (int j = 0; j < 4; j++)
                bf_[j] = *reinterpret_cast<const short8*>(Bc + browb + j * 2048 + (kb ^ swz));
            #pragma unroll
            for (int i = 0; i < 8; i++)
                #pragma unroll
                for (int j = 0; j < 4; j++)
                    acc[i][j] = __builtin_amdgcn_mfma_f32_16x16x32_bf16(af[i], bf_[j], acc[i][j], 0, 0, 0);
        }
        __builtin_amdgcn_s_setprio(0);

        // drain everything except A(t+2)'s 4 newest loads
        if (t < 14) { asm volatile("s_waitcnt vmcnt(4)" ::: "memory"); }
        else        { asm volatile("s_waitcnt vmcnt(0)" ::: "memory"); }
        __builtin_amdgcn_sched_barrier(0);
        __builtin_amdgcn_s_barrier();
        __builtin_amdgcn_sched_barrier(0);

        ia = (ia + 1 == 3) ? 0 : ia + 1;
    }

    // epilogue: + bias, scatter to original rows. C/D map: col=lane&15, row=(lane>>4)*4+reg
    const int ccol = lane & 15;
    const int crow = (lane >> 4) << 2;
    float bv[4];
    const float* bp = bias + branch * OUTF + n0 + wn;
    #pragma unroll
    for (int fn = 0; fn < 4; fn++) bv[fn] = bp[fn * 16 + ccol];
    #pragma unroll
    for (int fm = 0; fm < 8; fm++) {
        #pragma unroll
        for (int j = 0; j < 4; j++) {
            int gm = lt * 256 + wm + fm * 16 + crow + j;
            if (gm < cnt) {
                int orow = rowlist[rbase + gm];
                float* orp = out + (size_t)orow * OUTF + n0 + wn;
                #pragma unroll
                for (int fn = 0; fn < 4; fn++)
                    orp[fn * 16 + ccol] = acc[fm][fn][j] + bv[fn];
            }
        }
    }
}

// ---------------- fallback (direct, fp32 W) if ws is too small ----------------
__global__ __launch_bounds__(256, 3)
void k_gemm_fb(const float* __restrict__ x,
               const float* __restrict__ wf,
               const float* __restrict__ bias,
               const int* __restrict__ ws_i,
               const int* __restrict__ rowlist,
               float* __restrict__ out) {
    __shared__ unsigned short As[128][72];
    __shared__ unsigned short Bs[128][72];

    int t = (int)blockIdx.x;
    int branch = -1, ltile = 0, cnt = 0, rbase = 0;
    #pragma unroll
    for (int b = 0; b < NBR; b++) {
        if (branch < 0) {
            int c = ws_i[b];
            int nt = (c + 127) >> 7;
            if (t < nt) { branch = b; ltile = t; cnt = c; rbase = ws_i[4 + b]; }
            else t -= nt;
        }
    }
    if (branch < 0) return;

    const int tid = threadIdx.x;
    const int lane = tid & 63;
    const int wid = tid >> 6;
    const int wm = (wid & 1) << 6;
    const int wn = (wid >> 1) << 6;
    const int n0 = (int)blockIdx.y * 128;

    const int srow = tid >> 1;
    const int scol = (tid & 1) << 5;

    const int gmrow = ltile * 128 + srow;
    const int grow = (gmrow < cnt) ? rowlist[rbase + gmrow] : -1;
    const float* xsrc = x + (size_t)(grow < 0 ? 0 : grow) * OUTF + scol;
    const float* wfsrc = wf + ((size_t)branch << 20) + (size_t)(n0 + srow) * OUTF + scol;

    f32x4 acc[4][4];
    #pragma unroll
    for (int i = 0; i < 4; i++)
        #pragma unroll
        for (int j = 0; j < 4; j++)
            acc[i][j] = (f32x4){0.f, 0.f, 0.f, 0.f};

    for (int k0 = 0; k0 < OUTF; k0 += 64) {
        {
            unsigned short* dst = &As[srow][scol];
            if (grow >= 0) {
                const float4* s4 = reinterpret_cast<const float4*>(xsrc + k0);
                #pragma unroll
                for (int i = 0; i < 8; i += 2) {
                    float4 v0 = s4[i], v1 = s4[i + 1];
                    *reinterpret_cast<short8*>(dst + i * 4) = pack8(v0, v1);
                }
            } else {
                short8 z = (short8){0,0,0,0,0,0,0,0};
                #pragma unroll
                for (int i = 0; i < 8; i += 2) *reinterpret_cast<short8*>(dst + i * 4) = z;
            }
        }
        {
            unsigned short* dst = &Bs[srow][scol];
            const float4* s4 = reinterpret_cast<const float4*>(wfsrc + k0);
            #pragma unroll
            for (int i = 0; i < 8; i += 2) {
                float4 v0 = s4[i], v1 = s4[i + 1];
                *reinterpret_cast<short8*>(dst + i * 4) = pack8(v0, v1);
            }
        }
        __syncthreads();
        #pragma unroll
        for (int kk = 0; kk < 64; kk += 32) {
            const int krd = kk + (lane >> 4) * 8;
            short8 af[4], bf_[4];
            #pragma unroll
            for (int i = 0; i < 4; i++)
                af[i] = *reinterpret_cast<const short8*>(&As[wm + i * 16 + (lane & 15)][krd]);
            #pragma unroll
            for (int i = 0; i < 4; i++)
                bf_[i] = *reinterpret_cast<const short8*>(&Bs[wn + i * 16 + (lane & 15)][krd]);
            #pragma unroll
            for (int i = 0; i < 4; i++)
                #pragma unroll
                for (int j = 0; j < 4; j++)
                    acc[i][j] = __builtin_amdgcn_mfma_f32_16x16x32_bf16(af[i], bf_[j], acc[i][j], 0, 0, 0);
        }
        __syncthreads();
    }

    const int ccol = lane & 15;
    const int crow = (lane >> 4) << 2;
    float bv[4];
    const float* bp = bias + branch * OUTF + n0 + wn;
    #pragma unroll
    for (int fn = 0; fn < 4; fn++) bv[fn] = bp[fn * 16 + ccol];
    #pragma unroll
    for (int fm = 0; fm < 4; fm++) {
        #pragma unroll
        for (int j = 0; j < 4; j++) {
            int gm = ltile * 128 + wm + fm * 16 + crow + j;
            if (gm < cnt) {
                int orow = rowlist[rbase + gm];
                float* orp = out + (size_t)orow * OUTF + n0 + wn;
                #pragma unroll
                for (int fn = 0; fn < 4; fn++)
                    orp[fn * 16 + ccol] = acc[fm][fn][j] + bv[fn];
            }
        }
    }
}

extern "C" void kernel_launch(void* const* d_in, const int* in_sizes, int n_in,
                              void* d_out, int out_size, void* d_ws, size_t ws_size,
                              hipStream_t stream) {
    const float* x = (const float*)d_in[0];
    const int* feat = (const int*)d_in[1];
    const float* w = (const float*)d_in[2];
    const float* bias = (const float*)d_in[3];
    float* out = (float*)d_out;

    char* ws = (char*)d_ws;
    int* ws_i = (int*)ws;
    int* rowlist = (int*)(ws + 256);                       // 66560*4 = 266 KB
    const size_t WSW_OFF = (size_t)512 << 10;              // 512 KB
    const size_t XB_OFF = (size_t)9 << 20;                 // 9 MB
    unsigned short* wsw = (unsigned short*)(ws + WSW_OFF); // 8 MB
    unsigned short* xb = (unsigned short*)(ws + XB_OFF);   // 66560*2048 = 136.3 MB
    const size_t need_full = XB_OFF + (size_t)XBROWS * 2048;  // ~145.3 MB

    (void)hipMemsetAsync(ws_i, 0, 64, stream);
    k_count<<<NROWS / 256, 256, 0, stream>>>(feat, ws_i);
    k_prefix<<<1, 64, 0, stream>>>(ws_i);
    k_fill<<<NROWS / 256, 256, 0, stream>>>(feat, ws_i, rowlist);

    if (ws_size >= need_full) {
        k_convw<<<2048, 256, 0, stream>>>(w, wsw);
        k_convx<<<(XBROWS * 128) / 512, 512, 0, stream>>>(x, rowlist, xb);
        (void)hipFuncSetAttribute((const void*)k_gemm5,
                                  hipFuncAttributeMaxDynamicSharedMemorySize, 163840);
        k_gemm5<<<NWG, 512, 163840, stream>>>(xb, wsw, bias, ws_i, rowlist, out);
    } else {
        dim3 grid(NROWS / 128 + NBR, OUTF / 128);
        k_gemm_fb<<<grid, 256, 0, stream>>>(x, w, bias, ws_i, rowlist, out);
    }
}